// Round 1
// baseline (360.530 us; speedup 1.0000x reference)
//
#include <hip/hip_runtime.h>
#include <math.h>

// MemNN forward: B=64, S=200, T=32, E=128, V=50000, HOPS=3
#define VOCAB 50000
#define EMBD  128
#define SLEN  200
#define TOK   32
#define BATCH 64
#define QLEN  32
#define NSENT (BATCH*SLEN)        /* 12800 */
#define NTASK (4*NSENT + BATCH)   /* 51264 = 4*12816 */
#define TBL   ((size_t)VOCAB*EMBD)
#define VT    32                  /* v-tile for logits GEMM */

// ---------------------------------------------------------------------------
// Kernel A: gather-sum.  One wave per (table k, sentence bs):
//   G[k][bs][:] = sum_{t<32} A[k][x[bs*32+t]][:]
// plus 64 extra wave-tasks computing u0[b] = sum_t A[1][q[b,t]].
// Each lane accumulates float2 (64 lanes * 8B = full 512B row per load).
// ---------------------------------------------------------------------------
__global__ __launch_bounds__(256) void gather_kernel(
    const float* __restrict__ A, const int* __restrict__ x,
    const int* __restrict__ q, float* __restrict__ G, float* __restrict__ uF)
{
    int w    = blockIdx.x * 4 + (threadIdx.x >> 6);
    int lane = threadIdx.x & 63;
    const int*   idxp;
    const float* tbl;
    float*       outp;
    if (w < 4 * NSENT) {
        int k  = w / NSENT;
        int bs = w - k * NSENT;
        idxp = x + (size_t)bs * TOK;
        tbl  = A + (size_t)k * TBL;
        outp = G + (size_t)w * EMBD;
    } else {
        int b = w - 4 * NSENT;
        idxp = q + (size_t)b * QLEN;   // QLEN == TOK == 32
        tbl  = A + TBL;                // table A[1]
        outp = uF + (size_t)b * EMBD;
    }
    float ax = 0.f, ay = 0.f;
    #pragma unroll
    for (int t = 0; t < TOK; t++) {
        int idx = idxp[t];
        float2 v = ((const float2*)(tbl + (size_t)idx * EMBD))[lane];
        ax += v.x; ay += v.y;
    }
    float2 r; r.x = ax; r.y = ay;
    ((float2*)outp)[lane] = r;
}

// ---------------------------------------------------------------------------
// Wave-level reductions (wave = 64)
// ---------------------------------------------------------------------------
__device__ inline float waveSum(float v) {
    #pragma unroll
    for (int o = 32; o > 0; o >>= 1) v += __shfl_down(v, o, 64);
    return v;
}
__device__ inline float waveMax(float v) {
    #pragma unroll
    for (int o = 32; o > 0; o >>= 1) v = fmaxf(v, __shfl_down(v, o, 64));
    return v;
}

// ---------------------------------------------------------------------------
// Kernel B: the 3 hops.  One block (256 thr) per batch row.
//   score[s] = dot(G[k][b,s], u) + TA[s]*sum(u)
//   p = softmax(score)
//   u += sum_s p[s]*G[k+1][b,s] + sum_s p[s]*TC[s]
// ---------------------------------------------------------------------------
__global__ __launch_bounds__(256) void hops_kernel(
    const float* __restrict__ G, float* __restrict__ u,
    const float* __restrict__ TA, const float* __restrict__ TC)
{
    int b = blockIdx.x;
    int t = threadIdx.x;
    int lane = t & 63, wid = t >> 6;
    __shared__ __align__(16) float uL[EMBD];
    __shared__ float p[SLEN];
    __shared__ float red[4];
    __shared__ float pc[EMBD];

    if (t < EMBD) uL[t] = u[(size_t)b * EMBD + t];
    __syncthreads();

    for (int k = 0; k < 3; k++) {
        // ---- sum(u) ----
        float v = (t < EMBD) ? uL[t] : 0.f;
        v = waveSum(v);
        if (lane == 0) red[wid] = v;
        __syncthreads();
        float sumU = red[0] + red[1] + red[2] + red[3];
        __syncthreads();
        // ---- scores ----
        if (t < SLEN) {
            const float4* g4 = (const float4*)(G + ((size_t)k * NSENT + (size_t)b * SLEN + t) * EMBD);
            const float4* u4 = (const float4*)uL;
            float dot = 0.f;
            #pragma unroll 8
            for (int e = 0; e < EMBD / 4; e++) {
                float4 gg = g4[e], uu = u4[e];
                dot += gg.x * uu.x + gg.y * uu.y + gg.z * uu.z + gg.w * uu.w;
            }
            p[t] = dot + TA[t] * sumU;
        }
        __syncthreads();
        // ---- max ----
        float mv = (t < SLEN) ? p[t] : -3.4e38f;
        mv = waveMax(mv);
        if (lane == 0) red[wid] = mv;
        __syncthreads();
        float M = fmaxf(fmaxf(red[0], red[1]), fmaxf(red[2], red[3]));
        __syncthreads();
        // ---- exp ----
        float ev = 0.f;
        if (t < SLEN) { ev = __expf(p[t] - M); p[t] = ev; }
        __syncthreads();
        // ---- sum of exp ----
        float sv = waveSum(ev);
        if (lane == 0) red[wid] = sv;
        __syncthreads();
        float sumP = red[0] + red[1] + red[2] + red[3];
        __syncthreads();
        // ---- sum_s p[s]*TC[s] (unnormalized) ----
        float tcv = (t < SLEN) ? ev * TC[t] : 0.f;
        tcv = waveSum(tcv);
        if (lane == 0) red[wid] = tcv;
        __syncthreads();
        float pTC = red[0] + red[1] + red[2] + red[3];
        __syncthreads();
        // ---- combine: u += (sum_s p*G[k+1] + pTC)/sumP ----
        const float* Gc = G + ((size_t)(k + 1) * NSENT + (size_t)b * SLEN) * EMBD;
        int e = t & 127, sh = t >> 7;   // split s-range across two thread halves
        float acc = 0.f;
        for (int s = sh * 100; s < sh * 100 + 100; s++)
            acc += p[s] * Gc[(size_t)s * EMBD + e];
        if (sh) pc[e] = acc;
        __syncthreads();
        if (!sh) uL[e] = (acc + pc[e] + pTC) / sumP + uL[e];
        __syncthreads();
    }
    if (t < EMBD) u[(size_t)b * EMBD + t] = uL[t];
}

// ---------------------------------------------------------------------------
// Kernel C: logits[64,50000] = U[64,128] @ A3^T.  Block computes a 64b x 32v
// tile; A3-tile in LDS (stride 132 -> ~2-way conflicts), U-tile reads are
// quarter-wave broadcasts.  8 outputs/thread (4b x 2v), float4 over k.
// ---------------------------------------------------------------------------
__global__ __launch_bounds__(256) void logits_kernel(
    const float* __restrict__ A3, const float* __restrict__ u, float* __restrict__ out)
{
    __shared__ __align__(16) float Us[BATCH * EMBD];  // 32 KB
    __shared__ __align__(16) float As[VT * 132];      // 16.9 KB
    int t  = threadIdx.x;
    int v0 = blockIdx.x * VT;
    #pragma unroll
    for (int pp = 0; pp < 8; pp++) {
        int f = t * 4 + pp * 1024;
        *(float4*)&Us[f] = *(const float4*)&u[f];
    }
    #pragma unroll
    for (int pp = 0; pp < 4; pp++) {
        int f = t * 4 + pp * 1024;
        int r = f >> 7, c = f & 127;
        float4 val;
        if (v0 + r < VOCAB) val = *(const float4*)&A3[(size_t)(v0 + r) * EMBD + c];
        else { val.x = val.y = val.z = val.w = 0.f; }
        *(float4*)&As[r * 132 + c] = val;
    }
    __syncthreads();
    int lane = t & 63, w = t >> 6;
    int tx = lane & 15, ty = lane >> 4;
    int bb = w * 16 + ty * 4;
    float acc[4][2];
    #pragma unroll
    for (int i = 0; i < 4; i++) { acc[i][0] = 0.f; acc[i][1] = 0.f; }
    for (int k = 0; k < EMBD; k += 4) {
        float4 a[2], uu[4];
        a[0] = *(float4*)&As[tx * 132 + k];
        a[1] = *(float4*)&As[(tx + 16) * 132 + k];
        #pragma unroll
        for (int i = 0; i < 4; i++) uu[i] = *(float4*)&Us[(bb + i) * EMBD + k];
        #pragma unroll
        for (int i = 0; i < 4; i++)
            #pragma unroll
            for (int j = 0; j < 2; j++)
                acc[i][j] += uu[i].x * a[j].x + uu[i].y * a[j].y
                           + uu[i].z * a[j].z + uu[i].w * a[j].w;
    }
    #pragma unroll
    for (int i = 0; i < 4; i++) {
        int bI = bb + i;
        #pragma unroll
        for (int j = 0; j < 2; j++) {
            int v = v0 + tx + 16 * j;
            if (v < VOCAB) out[(size_t)bI * VOCAB + v] = acc[i][j];
        }
    }
}

// ---------------------------------------------------------------------------
// Kernel D: in-place log_softmax per row (1 block of 1024 thr per batch row).
// ---------------------------------------------------------------------------
__global__ __launch_bounds__(1024) void lsm_kernel(float* __restrict__ out)
{
    int b = blockIdx.x, t = threadIdx.x;
    float* row = out + (size_t)b * VOCAB;
    __shared__ float red[16];
    int lane = t & 63, wid = t >> 6;
    const int N4 = VOCAB / 4;  // 12500
    float m = -3.4e38f;
    for (int i = t; i < N4; i += 1024) {
        float4 v = ((const float4*)row)[i];
        m = fmaxf(m, fmaxf(fmaxf(v.x, v.y), fmaxf(v.z, v.w)));
    }
    m = waveMax(m);
    if (lane == 0) red[wid] = m;
    __syncthreads();
    float M = red[0];
    #pragma unroll
    for (int i = 1; i < 16; i++) M = fmaxf(M, red[i]);
    __syncthreads();
    float s = 0.f;
    for (int i = t; i < N4; i += 1024) {
        float4 v = ((const float4*)row)[i];
        s += __expf(v.x - M) + __expf(v.y - M) + __expf(v.z - M) + __expf(v.w - M);
    }
    s = waveSum(s);
    if (lane == 0) red[wid] = s;
    __syncthreads();
    float S = 0.f;
    #pragma unroll
    for (int i = 0; i < 16; i++) S += red[i];
    float lse = M + __logf(S);
    for (int i = t; i < N4; i += 1024) {
        float4 v = ((const float4*)row)[i];
        v.x -= lse; v.y -= lse; v.z -= lse; v.w -= lse;
        ((float4*)row)[i] = v;
    }
}

// ---------------------------------------------------------------------------
extern "C" void kernel_launch(void* const* d_in, const int* in_sizes, int n_in,
                              void* d_out, int out_size, void* d_ws, size_t ws_size,
                              hipStream_t stream)
{
    const float* A  = (const float*)d_in[0];   // [4, 50000, 128]
    const float* TA = (const float*)d_in[1];   // [200]
    const float* TC = (const float*)d_in[2];   // [200]
    const int*   x  = (const int*)d_in[3];     // [64, 200, 32]
    const int*   q  = (const int*)d_in[4];     // [64, 32]
    float* out = (float*)d_out;                // [64, 50000]

    float* G  = (float*)d_ws;                  // [4, 12800, 128] = 26.2 MB
    float* uF = G + (size_t)4 * NSENT * EMBD;  // [64, 128]

    gather_kernel<<<NTASK / 4, 256, 0, stream>>>(A, x, q, G, uF);
    hops_kernel<<<BATCH, 256, 0, stream>>>(G, uF, TA, TC);
    logits_kernel<<<(VOCAB + VT - 1) / VT, 256, 0, stream>>>(A + (size_t)3 * TBL, uF, out);
    lsm_kernel<<<BATCH, 1024, 0, stream>>>(out);
}

// Round 2
// 283.437 us; speedup vs baseline: 1.2720x; 1.2720x over previous
//
#include <hip/hip_runtime.h>
#include <math.h>

// MemNN forward: B=64, S=200, T=32, E=128, V=50000, HOPS=3
#define VOCAB 50000
#define EMBD  128
#define SLEN  200
#define TOK   32
#define BATCH 64
#define QLEN  32
#define NSENT (BATCH*SLEN)        /* 12800 */
#define NTASK (4*NSENT + BATCH)   /* 51264 = 4*12816 */
#define TBL   ((size_t)VOCAB*EMBD)
#define VT    32                  /* v-tile for logits GEMM */
#define NTILE ((VOCAB + VT - 1)/VT)   /* 1563 */

__device__ inline float bits2f(unsigned u){ union{unsigned u; float f;}c; c.u=u; return c.f; }
__device__ inline unsigned f2bits(float f){ union{float f; unsigned u;}c; c.f=f; return c.u; }
// round-to-nearest-even fp32->bf16, packed pair (lo in low 16)
__device__ inline unsigned pack_bf16(float lo, float hi){
    unsigned ul = f2bits(lo), uh = f2bits(hi);
    unsigned rl = (ul + 0x7fffu + ((ul>>16)&1u)) >> 16;
    unsigned rh = (uh + 0x7fffu + ((uh>>16)&1u)) >> 16;
    return rl | (rh<<16);
}

__device__ inline float waveSum(float v) {
    #pragma unroll
    for (int o = 32; o > 0; o >>= 1) v += __shfl_down(v, o, 64);
    return v;
}
__device__ inline float waveMax(float v) {
    #pragma unroll
    for (int o = 32; o > 0; o >>= 1) v = fmaxf(v, __shfl_down(v, o, 64));
    return v;
}

// ---------------------------------------------------------------------------
// Kernel 0: convert A (4 tables, fp32) -> bf16 copy in ws. 25.6M elems,
// 8 per thread, exact grid 12500x256.
// ---------------------------------------------------------------------------
__global__ __launch_bounds__(256) void conv_kernel(
    const float* __restrict__ A, unsigned* __restrict__ Ab)
{
    size_t i = ((size_t)blockIdx.x*256 + threadIdx.x)*8;
    float4 a = *(const float4*)(A+i);
    float4 b = *(const float4*)(A+i+4);
    uint4 o;
    o.x = pack_bf16(a.x,a.y); o.y = pack_bf16(a.z,a.w);
    o.z = pack_bf16(b.x,b.y); o.w = pack_bf16(b.z,b.w);
    *(uint4*)(Ab + i/2) = o;
}

// ---------------------------------------------------------------------------
// Kernel A: gather-sum from bf16 tables. One wave per (table k, sentence bs):
//   G[k][bs][:] = sum_t A[k][x[..t]][:]   (fp32 accumulate, fp32 G)
// Layout: 16 lanes x 8 bf16 (16B) cover one 256B row; wave covers 4 tokens
// per iteration; 8 fully-unrolled independent uint4 loads per lane.
// Last 64 wave-tasks compute u0[b] from q against table A[1].
// ---------------------------------------------------------------------------
__global__ __launch_bounds__(256) void gather_kernel(
    const unsigned* __restrict__ Ab, const int* __restrict__ x,
    const int* __restrict__ q, float* __restrict__ G, float* __restrict__ uF)
{
    int w    = blockIdx.x * 4 + (threadIdx.x >> 6);
    int lane = threadIdx.x & 63;
    const int*      idxp;
    const unsigned* tbl;
    float*          outp;
    if (w < 4 * NSENT) {
        int k  = w / NSENT;
        int bs = w - k * NSENT;
        idxp = x + (size_t)bs * TOK;
        tbl  = Ab + (size_t)k * (TBL/2);
        outp = G + (size_t)w * EMBD;
    } else {
        int b = w - 4 * NSENT;
        idxp = q + (size_t)b * QLEN;
        tbl  = Ab + (TBL/2);            // table A[1]
        outp = uF + (size_t)b * EMBD;
    }
    int tg = lane >> 4;   // token subgroup 0..3
    int sl = lane & 15;   // 8-elem slice within row
    int idxs[8];
    #pragma unroll
    for (int i = 0; i < 8; i++) idxs[i] = idxp[i*4 + tg];
    float acc[8];
    #pragma unroll
    for (int c = 0; c < 8; c++) acc[c] = 0.f;
    #pragma unroll
    for (int i = 0; i < 8; i++) {
        uint4 v = *(const uint4*)(tbl + (size_t)idxs[i]*64 + sl*4);
        acc[0] += bits2f(v.x<<16); acc[1] += bits2f(v.x&0xffff0000u);
        acc[2] += bits2f(v.y<<16); acc[3] += bits2f(v.y&0xffff0000u);
        acc[4] += bits2f(v.z<<16); acc[5] += bits2f(v.z&0xffff0000u);
        acc[6] += bits2f(v.w<<16); acc[7] += bits2f(v.w&0xffff0000u);
    }
    #pragma unroll
    for (int c = 0; c < 8; c++) {
        acc[c] += __shfl_xor(acc[c], 32, 64);
        acc[c] += __shfl_xor(acc[c], 16, 64);
    }
    if (lane < 32) {
        int g = lane & 15, h = lane >> 4;
        float4 r; r.x = acc[4*h]; r.y = acc[4*h+1]; r.z = acc[4*h+2]; r.w = acc[4*h+3];
        ((float4*)outp)[2*g + h] = r;
    }
}

// ---------------------------------------------------------------------------
// Kernel B: 3 hops, one block (1024 thr) per batch row, G in fp32.
// ---------------------------------------------------------------------------
__global__ __launch_bounds__(1024) void hops_kernel(
    const float* __restrict__ G, float* __restrict__ u,
    const float* __restrict__ TA, const float* __restrict__ TC)
{
    int b = blockIdx.x;
    int t = threadIdx.x;
    int lane = t & 63, wid = t >> 6;
    __shared__ __align__(16) float uL[EMBD];
    __shared__ float p[256];
    __shared__ float red[16], red2[16];
    __shared__ float pc[7*EMBD];

    if (t < EMBD) uL[t] = u[(size_t)b * EMBD + t];
    __syncthreads();

    for (int k = 0; k < 3; k++) {
        // ---- sum(u) ----
        float v = (t < EMBD) ? uL[t] : 0.f;
        v = waveSum(v);
        if (lane == 0) red[wid] = v;
        __syncthreads();
        float sumU = 0.f;
        #pragma unroll
        for (int i = 0; i < 16; i++) sumU += red[i];
        // ---- scores: 4 threads per sentence ----
        int s = t >> 2, qd = t & 3;
        if (s < SLEN) {
            const float4* g4 = (const float4*)(G + ((size_t)k*NSENT + (size_t)b*SLEN + s)*EMBD);
            const float4* u4 = (const float4*)uL;
            float dot = 0.f;
            #pragma unroll
            for (int e = 0; e < 8; e++) {
                float4 gg = g4[qd*8+e], uu = u4[qd*8+e];
                dot += gg.x*uu.x + gg.y*uu.y + gg.z*uu.z + gg.w*uu.w;
            }
            dot += __shfl_xor(dot, 1, 64);
            dot += __shfl_xor(dot, 2, 64);
            if (qd == 0) p[s] = dot + TA[s]*sumU;
        }
        __syncthreads();
        // ---- max ----
        float mv = (t < SLEN) ? p[t] : -3.4e38f;
        mv = waveMax(mv);
        if (lane == 0) red[wid] = mv;
        __syncthreads();
        float M = -3.4e38f;
        #pragma unroll
        for (int i = 0; i < 16; i++) M = fmaxf(M, red[i]);
        __syncthreads();
        // ---- exp, sumexp, p.TC ----
        float ev = 0.f, tc = 0.f;
        if (t < SLEN) { ev = __expf(p[t] - M); p[t] = ev; tc = ev * TC[t]; }
        float sv = waveSum(ev);
        float tv = waveSum(tc);
        if (lane == 0) { red[wid] = sv; red2[wid] = tv; }
        __syncthreads();
        float sumP = 0.f, pTC = 0.f;
        #pragma unroll
        for (int i = 0; i < 16; i++) { sumP += red[i]; pTC += red2[i]; }
        // ---- combine: u += (sum_s p*G[k+1] + pTC)/sumP ----
        const float* Gc = G + ((size_t)(k+1)*NSENT + (size_t)b*SLEN)*EMBD;
        int e = t & 127, ch = t >> 7;   // 8 chunks of 25 sentences
        float acc = 0.f;
        for (int s2 = ch*25; s2 < ch*25 + 25; s2++)
            acc += p[s2] * Gc[(size_t)s2*EMBD + e];
        if (ch > 0) pc[(ch-1)*EMBD + e] = acc;
        __syncthreads();
        if (ch == 0) {
            #pragma unroll
            for (int c = 0; c < 7; c++) acc += pc[c*EMBD + e];
            uL[e] += (acc + pTC) / sumP;
        }
        __syncthreads();
    }
    if (t < EMBD) u[(size_t)b * EMBD + t] = uL[t];
}

// ---------------------------------------------------------------------------
// Kernel C: logits[64,50000] = U @ A3^T (A3 in bf16), fused per-(row,tile)
// online-softmax partials (max, sumexp) written to ws.
// ---------------------------------------------------------------------------
__global__ __launch_bounds__(256) void logits_kernel(
    const unsigned* __restrict__ A3b, const float* __restrict__ u,
    float* __restrict__ out, float* __restrict__ part)
{
    __shared__ __align__(16) float Us[BATCH * EMBD];  // 32 KB
    __shared__ __align__(16) float As[VT * 132];      // 16.9 KB
    int t  = threadIdx.x;
    int v0 = blockIdx.x * VT;
    #pragma unroll
    for (int pp = 0; pp < 8; pp++) {
        int f = t * 4 + pp * 1024;
        *(float4*)&Us[f] = *(const float4*)&u[f];
    }
    {   // stage A3 tile bf16->fp32: 16 elems per thread
        int f = t * 16;
        int r = f >> 7, c = f & 127;
        int vv = v0 + r;
        float vals[16];
        if (vv < VOCAB) {
            const unsigned* src = A3b + (size_t)vv*64 + (c>>1);
            uint4 p0 = *(const uint4*)src;
            uint4 p1 = *(const uint4*)(src + 4);
            vals[0]=bits2f(p0.x<<16);  vals[1]=bits2f(p0.x&0xffff0000u);
            vals[2]=bits2f(p0.y<<16);  vals[3]=bits2f(p0.y&0xffff0000u);
            vals[4]=bits2f(p0.z<<16);  vals[5]=bits2f(p0.z&0xffff0000u);
            vals[6]=bits2f(p0.w<<16);  vals[7]=bits2f(p0.w&0xffff0000u);
            vals[8]=bits2f(p1.x<<16);  vals[9]=bits2f(p1.x&0xffff0000u);
            vals[10]=bits2f(p1.y<<16); vals[11]=bits2f(p1.y&0xffff0000u);
            vals[12]=bits2f(p1.z<<16); vals[13]=bits2f(p1.z&0xffff0000u);
            vals[14]=bits2f(p1.w<<16); vals[15]=bits2f(p1.w&0xffff0000u);
        } else {
            #pragma unroll
            for (int i = 0; i < 16; i++) vals[i] = 0.f;
        }
        #pragma unroll
        for (int i = 0; i < 16; i += 4)
            *(float4*)&As[r*132 + c + i] = *(float4*)&vals[i];
    }
    __syncthreads();
    int lane = t & 63, w = t >> 6;
    int tx = lane & 15, ty = lane >> 4;
    int bb = w * 16 + ty * 4;
    float acc[4][2];
    #pragma unroll
    for (int i = 0; i < 4; i++) { acc[i][0] = 0.f; acc[i][1] = 0.f; }
    for (int k = 0; k < EMBD; k += 4) {
        float4 a[2], uu[4];
        a[0] = *(float4*)&As[tx * 132 + k];
        a[1] = *(float4*)&As[(tx + 16) * 132 + k];
        #pragma unroll
        for (int i = 0; i < 4; i++) uu[i] = *(float4*)&Us[(bb + i) * EMBD + k];
        #pragma unroll
        for (int i = 0; i < 4; i++)
            #pragma unroll
            for (int j = 0; j < 2; j++)
                acc[i][j] += uu[i].x * a[j].x + uu[i].y * a[j].y
                           + uu[i].z * a[j].z + uu[i].w * a[j].w;
    }
    bool val0 = (v0 + tx) < VOCAB, val1 = (v0 + tx + 16) < VOCAB;
    #pragma unroll
    for (int i = 0; i < 4; i++) {
        int bI = bb + i;
        if (val0) out[(size_t)bI * VOCAB + v0 + tx]      = acc[i][0];
        if (val1) out[(size_t)bI * VOCAB + v0 + tx + 16] = acc[i][1];
        // tile-local max + sumexp across the 16 tx lanes
        float m = fmaxf(val0 ? acc[i][0] : -3.4e38f, val1 ? acc[i][1] : -3.4e38f);
        #pragma unroll
        for (int o = 1; o < 16; o <<= 1) m = fmaxf(m, __shfl_xor(m, o, 64));
        float se = (val0 ? __expf(acc[i][0] - m) : 0.f)
                 + (val1 ? __expf(acc[i][1] - m) : 0.f);
        #pragma unroll
        for (int o = 1; o < 16; o <<= 1) se += __shfl_xor(se, o, 64);
        if (tx == 0) {
            float2 pr; pr.x = m; pr.y = se;
            ((float2*)part)[(size_t)bI * NTILE + blockIdx.x] = pr;
        }
    }
}

// ---------------------------------------------------------------------------
// Kernel D: per-row lse from tile partials (64 blocks x 256 thr).
// ---------------------------------------------------------------------------
__global__ __launch_bounds__(256) void lse_kernel(
    const float* __restrict__ part, float* __restrict__ lse)
{
    int r = blockIdx.x, t = threadIdx.x;
    int lane = t & 63, wid = t >> 6;
    __shared__ float sm[4], sl[4];
    const float2* P = (const float2*)part + (size_t)r * NTILE;
    float M = -3.4e38f, L = 0.f;
    for (int i = t; i < NTILE; i += 256) {
        float2 pr = P[i];
        float m2 = fmaxf(M, pr.x);
        L = L * __expf(M - m2) + pr.y * __expf(pr.x - m2);
        M = m2;
    }
    #pragma unroll
    for (int o = 1; o < 64; o <<= 1) {
        float Mo = __shfl_xor(M, o, 64), Lo = __shfl_xor(L, o, 64);
        float m2 = fmaxf(M, Mo);
        L = L * __expf(M - m2) + Lo * __expf(Mo - m2);
        M = m2;
    }
    if (lane == 0) { sm[wid] = M; sl[wid] = L; }
    __syncthreads();
    if (t == 0) {
        float Mf = -3.4e38f, Lf = 0.f;
        #pragma unroll
        for (int i = 0; i < 4; i++) {
            float m2 = fmaxf(Mf, sm[i]);
            Lf = Lf * __expf(Mf - m2) + sl[i] * __expf(sm[i] - m2);
            Mf = m2;
        }
        lse[r] = Mf + __logf(Lf);
    }
}

// ---------------------------------------------------------------------------
// Kernel E: normalize in place (3125 blocks x 256 thr, 1 float4/thread).
// ---------------------------------------------------------------------------
__global__ __launch_bounds__(256) void norm_kernel(
    float* __restrict__ out, const float* __restrict__ lse)
{
    int gid = blockIdx.x * 256 + threadIdx.x;   // 0..799999
    int b = gid / (VOCAB/4);                     // 12500 float4 per row
    float l = lse[b];
    float4 v = ((float4*)out)[gid];
    v.x -= l; v.y -= l; v.z -= l; v.w -= l;
    ((float4*)out)[gid] = v;
}

// ---------------------------------------------------------------------------
extern "C" void kernel_launch(void* const* d_in, const int* in_sizes, int n_in,
                              void* d_out, int out_size, void* d_ws, size_t ws_size,
                              hipStream_t stream)
{
    const float* A  = (const float*)d_in[0];   // [4, 50000, 128]
    const float* TA = (const float*)d_in[1];   // [200]
    const float* TC = (const float*)d_in[2];   // [200]
    const int*   x  = (const int*)d_in[3];     // [64, 200, 32]
    const int*   q  = (const int*)d_in[4];     // [64, 32]
    float* out = (float*)d_out;                // [64, 50000]

    // ws layout: bf16 A copy | G fp32 | uF | partials | lse   (~78.3 MB)
    unsigned* Ab = (unsigned*)d_ws;                       // 4*TBL/2 uints = 51.2 MB
    float* G   = (float*)((char*)d_ws + (size_t)4*TBL*2); // [4,12800,128] = 26.2 MB
    float* uF  = G + (size_t)4*NSENT*EMBD;                // [64,128]
    float* part= uF + (size_t)BATCH*EMBD;                 // [64,1563,2] = 800 KB
    float* lse = part + (size_t)BATCH*NTILE*2;            // [64]

    conv_kernel  <<<12500, 256, 0, stream>>>(A, Ab);
    gather_kernel<<<NTASK/4, 256, 0, stream>>>(Ab, x, q, G, uF);
    hops_kernel  <<<BATCH, 1024, 0, stream>>>(G, uF, TA, TC);
    logits_kernel<<<NTILE, 256, 0, stream>>>(Ab + 3*(TBL/2), uF, out, part);
    lse_kernel   <<<BATCH, 256, 0, stream>>>(part, lse);
    norm_kernel  <<<BATCH*(VOCAB/4)/256, 256, 0, stream>>>(out, lse);
}

// Round 3
// 277.695 us; speedup vs baseline: 1.2983x; 1.0207x over previous
//
#include <hip/hip_runtime.h>
#include <math.h>

// MemNN forward: B=64, S=200, T=32, E=128, V=50000, HOPS=3
#define VOCAB 50000
#define EMBD  128
#define SLEN  200
#define TOK   32
#define BATCH 64
#define QLEN  32
#define NSENT (BATCH*SLEN)        /* 12800 */
#define NTASK (4*NSENT + BATCH)   /* 51264 = 4*12816 */
#define TBL   ((size_t)VOCAB*EMBD)
#define NTILE 3125                /* 16-wide vocab tiles for MFMA logits */

typedef short short8 __attribute__((ext_vector_type(8)));
typedef float f32x4  __attribute__((ext_vector_type(4)));

__device__ inline float bits2f(unsigned u){ union{unsigned u; float f;}c; c.u=u; return c.f; }
__device__ inline unsigned f2bits(float f){ union{float f; unsigned u;}c; c.f=f; return c.u; }
// round-to-nearest-even fp32->bf16, packed pair (lo in low 16)
__device__ inline unsigned pack_bf16(float lo, float hi){
    unsigned ul = f2bits(lo), uh = f2bits(hi);
    unsigned rl = (ul + 0x7fffu + ((ul>>16)&1u)) >> 16;
    unsigned rh = (uh + 0x7fffu + ((uh>>16)&1u)) >> 16;
    return rl | (rh<<16);
}
__device__ inline unsigned short bf16of(float f){
    unsigned u = f2bits(f);
    return (unsigned short)((u + 0x7fffu + ((u>>16)&1u)) >> 16);
}

__device__ inline float waveSum(float v) {
    #pragma unroll
    for (int o = 32; o > 0; o >>= 1) v += __shfl_down(v, o, 64);
    return v;
}
__device__ inline float waveMax(float v) {
    #pragma unroll
    for (int o = 32; o > 0; o >>= 1) v = fmaxf(v, __shfl_down(v, o, 64));
    return v;
}

// ---------------------------------------------------------------------------
// Kernel 0: convert A (4 tables, fp32) -> bf16 copy in ws.
// ---------------------------------------------------------------------------
__global__ __launch_bounds__(256) void conv_kernel(
    const float* __restrict__ A, unsigned* __restrict__ Ab)
{
    size_t i = ((size_t)blockIdx.x*256 + threadIdx.x)*8;
    float4 a = *(const float4*)(A+i);
    float4 b = *(const float4*)(A+i+4);
    uint4 o;
    o.x = pack_bf16(a.x,a.y); o.y = pack_bf16(a.z,a.w);
    o.z = pack_bf16(b.x,b.y); o.w = pack_bf16(b.z,b.w);
    *(uint4*)(Ab + i/2) = o;
}

// ---------------------------------------------------------------------------
// Kernel A: gather-sum from bf16 tables (fp32 accumulate, fp32 G).
// XCD-swizzled: blocks with blockIdx%8 in {2k,2k+1} gather table k, so each
// per-XCD L2 only sees one 12.8 MB table (better hit rate than all four).
// ---------------------------------------------------------------------------
__global__ __launch_bounds__(256) void gather_kernel(
    const unsigned* __restrict__ Ab, const int* __restrict__ x,
    const int* __restrict__ q, float* __restrict__ G, float* __restrict__ uF)
{
    int B = blockIdx.x;
    int wid = threadIdx.x >> 6;
    int w;
    if (B < 12800) {
        int k = (B & 7) >> 1;
        int i = (B >> 3)*2 + (B & 1);       // 0..3199 within table
        w = k*NSENT + i*4 + wid;
    } else {
        w = B*4 + wid;                      // q-tasks: w in [51200, 51264)
    }
    int lane = threadIdx.x & 63;
    const int*      idxp;
    const unsigned* tbl;
    bool qtask = (w >= 4*NSENT);
    float* outp;
    if (!qtask) {
        int k  = w / NSENT;
        int bs = w - k * NSENT;
        idxp = x + (size_t)bs * TOK;
        tbl  = Ab + (size_t)k * (TBL/2);
        outp = G + (size_t)w * EMBD;
    } else {
        int b = w - 4 * NSENT;
        idxp = q + (size_t)b * QLEN;
        tbl  = Ab + (TBL/2);                // table A[1]
        outp = uF + (size_t)b * EMBD;
    }
    int tg = lane >> 4;   // token subgroup 0..3
    int sl = lane & 15;   // 8-elem slice within row
    int idxs[8];
    #pragma unroll
    for (int i = 0; i < 8; i++) idxs[i] = idxp[i*4 + tg];
    float acc[8];
    #pragma unroll
    for (int c = 0; c < 8; c++) acc[c] = 0.f;
    #pragma unroll
    for (int i = 0; i < 8; i++) {
        uint4 v = *(const uint4*)(tbl + (size_t)idxs[i]*64 + sl*4);
        acc[0] += bits2f(v.x<<16); acc[1] += bits2f(v.x&0xffff0000u);
        acc[2] += bits2f(v.y<<16); acc[3] += bits2f(v.y&0xffff0000u);
        acc[4] += bits2f(v.z<<16); acc[5] += bits2f(v.z&0xffff0000u);
        acc[6] += bits2f(v.w<<16); acc[7] += bits2f(v.w&0xffff0000u);
    }
    #pragma unroll
    for (int c = 0; c < 8; c++) {
        acc[c] += __shfl_xor(acc[c], 32, 64);
        acc[c] += __shfl_xor(acc[c], 16, 64);
    }
    if (lane < 32) {
        int g = lane & 15, h = lane >> 4;
        float4 r; r.x = acc[4*h]; r.y = acc[4*h+1]; r.z = acc[4*h+2]; r.w = acc[4*h+3];
        ((float4*)outp)[2*g + h] = r;
    }
}

// ---------------------------------------------------------------------------
// Kernel B: 3 hops, one block (1024 thr) per batch row, G fp32.
// The combine phase of hop k caches G[k+1][b] in LDS (padded stride 132),
// which the score phase of hop k+1 then reads: each G slice read once.
// Epilogue emits u as bf16 for the MFMA logits kernel.
// ---------------------------------------------------------------------------
__global__ __launch_bounds__(1024) void hops_kernel(
    const float* __restrict__ G, const float* __restrict__ uF,
    const float* __restrict__ TA, const float* __restrict__ TC,
    unsigned short* __restrict__ ub)
{
    int b = blockIdx.x;
    int t = threadIdx.x;
    int lane = t & 63, wid = t >> 6;
    __shared__ __align__(16) float Gs[SLEN*132];   // 105.6 KB cached G slice
    __shared__ __align__(16) float uL[EMBD];
    __shared__ float p[256];
    __shared__ float red[16], red2[16];
    __shared__ float pc[7*EMBD];

    if (t < EMBD) uL[t] = uF[(size_t)b * EMBD + t];
    __syncthreads();

    for (int k = 0; k < 3; k++) {
        // ---- sum(u) ----
        float v = (t < EMBD) ? uL[t] : 0.f;
        v = waveSum(v);
        if (lane == 0) red[wid] = v;
        __syncthreads();
        float sumU = 0.f;
        #pragma unroll
        for (int i = 0; i < 16; i++) sumU += red[i];
        // ---- scores: 4 threads per sentence ----
        int s = t >> 2, qd = t & 3;
        if (s < SLEN) {
            const float4* u4 = (const float4*)uL;
            float dot = 0.f;
            if (k == 0) {
                const float4* g4 = (const float4*)(G + ((size_t)b*SLEN + s)*EMBD);
                #pragma unroll
                for (int e = 0; e < 8; e++) {
                    float4 gg = g4[qd*8+e], uu = u4[qd*8+e];
                    dot += gg.x*uu.x + gg.y*uu.y + gg.z*uu.z + gg.w*uu.w;
                }
            } else {
                const float4* g4 = (const float4*)(Gs + s*132);
                #pragma unroll
                for (int e = 0; e < 8; e++) {
                    float4 gg = g4[qd*8+e], uu = u4[qd*8+e];
                    dot += gg.x*uu.x + gg.y*uu.y + gg.z*uu.z + gg.w*uu.w;
                }
            }
            dot += __shfl_xor(dot, 1, 64);
            dot += __shfl_xor(dot, 2, 64);
            if (qd == 0) p[s] = dot + TA[s]*sumU;
        }
        __syncthreads();
        // ---- max ----
        float mv = (t < SLEN) ? p[t] : -3.4e38f;
        mv = waveMax(mv);
        if (lane == 0) red[wid] = mv;
        __syncthreads();
        float M = -3.4e38f;
        #pragma unroll
        for (int i = 0; i < 16; i++) M = fmaxf(M, red[i]);
        __syncthreads();
        // ---- exp, sumexp, p.TC ----
        float ev = 0.f, tc = 0.f;
        if (t < SLEN) { ev = __expf(p[t] - M); p[t] = ev; tc = ev * TC[t]; }
        float sv = waveSum(ev);
        float tv = waveSum(tc);
        if (lane == 0) { red[wid] = sv; red2[wid] = tv; }
        __syncthreads();
        float sumP = 0.f, pTC = 0.f;
        #pragma unroll
        for (int i = 0; i < 16; i++) { sumP += red[i]; pTC += red2[i]; }
        // ---- combine: u += (sum_s p*G[k+1] + pTC)/sumP ; cache slice in LDS
        const float* Gc = G + ((size_t)(k+1)*NSENT + (size_t)b*SLEN)*EMBD;
        int e = t & 127, ch = t >> 7;   // 8 chunks of 25 sentences
        float acc = 0.f;
        for (int s2 = ch*25; s2 < ch*25 + 25; s2++) {
            float g = Gc[(size_t)s2*EMBD + e];
            Gs[s2*132 + e] = g;
            acc += p[s2] * g;
        }
        if (ch > 0) pc[(ch-1)*EMBD + e] = acc;
        __syncthreads();
        if (ch == 0) {
            #pragma unroll
            for (int c = 0; c < 7; c++) acc += pc[c*EMBD + e];
            uL[e] += (acc + pTC) / sumP;
        }
        __syncthreads();
    }
    if (t < EMBD) ub[(size_t)b * EMBD + t] = bf16of(uL[t]);
}

// ---------------------------------------------------------------------------
// Kernel C: MFMA logits. One wave per 16-vocab tile, all 64 batches.
// D = U[64,128] @ A3^T via 4(bt) x 4(kc) mfma_f32_16x16x32_bf16.
// A-frag:  U[bt*16 + (lane&15)][kc*32 + (lane>>4)*8 + i]
// B-frag:  A3[v0 + (lane&15)][kc*32 + (lane>>4)*8 + i]   (B[k][n]=A3[n][k])
// C/D:     row=(lane>>4)*4+reg, col=lane&15
// Fused per-(row,tile) softmax partials (max, sumexp) -> part.
// ---------------------------------------------------------------------------
__global__ __launch_bounds__(256) void logits_mfma(
    const unsigned short* __restrict__ A3b, const unsigned short* __restrict__ ub,
    float* __restrict__ out, float* __restrict__ part)
{
    int w = blockIdx.x*4 + (threadIdx.x >> 6);
    if (w >= NTILE) return;
    int lane = threadIdx.x & 63;
    int col = lane & 15, quad = lane >> 4;
    int v0 = w * 16;

    short8 af[4][4];
    #pragma unroll
    for (int bt = 0; bt < 4; bt++)
        #pragma unroll
        for (int kc = 0; kc < 4; kc++)
            af[bt][kc] = *(const short8*)(ub + (bt*16 + col)*EMBD + kc*32 + quad*8);

    f32x4 acc[4];
    #pragma unroll
    for (int bt = 0; bt < 4; bt++) acc[bt] = (f32x4){0.f, 0.f, 0.f, 0.f};

    #pragma unroll
    for (int kc = 0; kc < 4; kc++) {
        short8 bf = *(const short8*)(A3b + (size_t)(v0 + col)*EMBD + kc*32 + quad*8);
        #pragma unroll
        for (int bt = 0; bt < 4; bt++)
            acc[bt] = __builtin_amdgcn_mfma_f32_16x16x32_bf16(af[bt][kc], bf, acc[bt], 0, 0, 0);
    }

    #pragma unroll
    for (int bt = 0; bt < 4; bt++) {
        #pragma unroll
        for (int r = 0; r < 4; r++) {
            int bI = bt*16 + quad*4 + r;
            out[(size_t)bI * VOCAB + v0 + col] = acc[bt][r];
        }
        #pragma unroll
        for (int r = 0; r < 4; r++) {
            float m = acc[bt][r];
            #pragma unroll
            for (int o = 1; o < 16; o <<= 1) m = fmaxf(m, __shfl_xor(m, o, 64));
            float se = __expf(acc[bt][r] - m);
            #pragma unroll
            for (int o = 1; o < 16; o <<= 1) se += __shfl_xor(se, o, 64);
            if (col == 0) {
                int bI = bt*16 + quad*4 + r;
                float2 pr; pr.x = m; pr.y = se;
                ((float2*)part)[(size_t)bI * NTILE + w] = pr;
            }
        }
    }
}

// ---------------------------------------------------------------------------
// Kernel D: fused lse + normalize. 64 rows x 49 chunks; each block reduces
// the row's 3125 tile-partials (L2-hot) then normalizes its 1024-float chunk.
// ---------------------------------------------------------------------------
__global__ __launch_bounds__(256) void norm_kernel(
    float* __restrict__ out, const float* __restrict__ part)
{
    int b = blockIdx.x / 49, c = blockIdx.x % 49;
    int t = threadIdx.x, lane = t & 63, wid = t >> 6;
    __shared__ float sm[4], sl[4];
    const float2* P = (const float2*)part + (size_t)b * NTILE;
    float M = -3.4e38f, L = 0.f;
    for (int i = t; i < NTILE; i += 256) {
        float2 pr = P[i];
        float m2 = fmaxf(M, pr.x);
        L = L * __expf(M - m2) + pr.y * __expf(pr.x - m2);
        M = m2;
    }
    #pragma unroll
    for (int o = 1; o < 64; o <<= 1) {
        float Mo = __shfl_xor(M, o, 64), Lo = __shfl_xor(L, o, 64);
        float m2 = fmaxf(M, Mo);
        L = L * __expf(M - m2) + Lo * __expf(Mo - m2);
        M = m2;
    }
    if (lane == 0) { sm[wid] = M; sl[wid] = L; }
    __syncthreads();
    float Mf = -3.4e38f, Lf = 0.f;
    #pragma unroll
    for (int i = 0; i < 4; i++) {
        float m2 = fmaxf(Mf, sm[i]);
        Lf = Lf * __expf(Mf - m2) + sl[i] * __expf(sm[i] - m2);
        Mf = m2;
    }
    float lse = Mf + __logf(Lf);
    int f4 = c * 256 + t;
    if (f4 < VOCAB/4) {
        float4* rowp = (float4*)(out + (size_t)b * VOCAB);
        float4 v = rowp[f4];
        v.x -= lse; v.y -= lse; v.z -= lse; v.w -= lse;
        rowp[f4] = v;
    }
}

// ---------------------------------------------------------------------------
extern "C" void kernel_launch(void* const* d_in, const int* in_sizes, int n_in,
                              void* d_out, int out_size, void* d_ws, size_t ws_size,
                              hipStream_t stream)
{
    const float* A  = (const float*)d_in[0];   // [4, 50000, 128]
    const float* TA = (const float*)d_in[1];   // [200]
    const float* TC = (const float*)d_in[2];   // [200]
    const int*   x  = (const int*)d_in[3];     // [64, 200, 32]
    const int*   q  = (const int*)d_in[4];     // [64, 32]
    float* out = (float*)d_out;                // [64, 50000]

    // ws: Ab bf16 (51.2MB) | G fp32 (26.2MB) | uF | ub | part (1.6MB)
    unsigned* Ab = (unsigned*)d_ws;
    float* G   = (float*)((char*)d_ws + (size_t)4*TBL*2);
    float* uF  = G + (size_t)4*NSENT*EMBD;
    unsigned short* ubp = (unsigned short*)(uF + (size_t)BATCH*EMBD);
    float* part = (float*)(ubp + (size_t)BATCH*EMBD);

    conv_kernel  <<<12500, 256, 0, stream>>>(A, Ab);
    gather_kernel<<<NTASK/4, 256, 0, stream>>>(Ab, x, q, G, uF);
    hops_kernel  <<<BATCH, 1024, 0, stream>>>(G, uF, TA, TC, ubp);
    logits_mfma  <<<(NTILE+3)/4, 256, 0, stream>>>(
        (const unsigned short*)Ab + (size_t)3*TBL, ubp, out, part);
    norm_kernel  <<<BATCH*49, 256, 0, stream>>>(out, part);
}